// Round 1
// baseline (336.936 us; speedup 1.0000x reference)
//
#include <hip/hip_runtime.h>
#include <hip/hip_bf16.h>
#include <stdint.h>

// ---------- helpers ----------
__device__ __forceinline__ unsigned short f2bf(float f) {
    __hip_bfloat16 h = __float2bfloat16(f);   // RNE, matches JAX astype
    return *reinterpret_cast<unsigned short*>(&h);
}
__device__ __forceinline__ float bf2f(unsigned short u) {
    __hip_bfloat16 h = *reinterpret_cast<__hip_bfloat16*>(&u);
    return __bfloat162float(h);
}

typedef __attribute__((ext_vector_type(8))) short bf16x8;
typedef __attribute__((ext_vector_type(4))) float f32x4;

__device__ __forceinline__ void async16(const void* g, void* l) {
    __builtin_amdgcn_global_load_lds(
        (const __attribute__((address_space(1))) unsigned int*)g,
        (__attribute__((address_space(3))) unsigned int*)l,
        16, 0, 0);
}

// ---------- kernel 1: ternary-quantize weight (replicates JAX bf16 per-op rounding) ----------
// flat groups of 64; one 64-lane wave per group.
__global__ __launch_bounds__(256) void quant_kernel(const float* __restrict__ W,
                                                    unsigned short* __restrict__ Wq) {
    int idx = blockIdx.x * 256 + threadIdx.x;
    float wf = W[idx];
    float wbf = bf2f(f2bf(wf));            // w = weight.astype(bf16)
    float a = fabsf(wbf);
    float s = a;
    #pragma unroll
    for (int off = 32; off; off >>= 1) s += __shfl_xor(s, off, 64);
    float mean = s * (1.0f / 64.0f);       // f32 accumulation (JAX upcasts bf16 mean)
    float sf = bf2f(f2bf(mean));           // cast result back to bf16
    sf = fmaxf(sf, 1.0011718e-08f);        // clip(scale, 1e-8) in bf16 domain
    float quot = bf2f(f2bf(wbf / sf));     // bf16 division = f32 div then bf16 round
    float q = rintf(quot);                 // round half-to-even
    q = fminf(1.0f, fmaxf(-1.0f, q));
    float qs = q * sf;                     // exact bf16 value (q in {-1,0,1})
    float d  = bf2f(f2bf(qs - wbf));       // bf16 subtraction rounding
    Wq[idx] = f2bf(wbf + d);               // bf16 add rounding -> forward weight
}

// ---------- kernel 2: RMS-norm rows of 4096, write bf16 ----------
__global__ __launch_bounds__(256) void norm_kernel(const float* __restrict__ X,
                                                   unsigned short* __restrict__ Xb) {
    __shared__ float red[4];
    const long long row = blockIdx.x;
    const float4* xr = (const float4*)(X + row * 4096);
    const int t = threadIdx.x;
    float4 v[4];
    float ss = 0.f;
    #pragma unroll
    for (int i = 0; i < 4; ++i) {
        v[i] = xr[i * 256 + t];
        ss += v[i].x * v[i].x + v[i].y * v[i].y + v[i].z * v[i].z + v[i].w * v[i].w;
    }
    #pragma unroll
    for (int off = 32; off; off >>= 1) ss += __shfl_xor(ss, off, 64);
    if ((t & 63) == 0) red[t >> 6] = ss;
    __syncthreads();
    const float tot = red[0] + red[1] + red[2] + red[3];
    const float scale = 1.0f / sqrtf(tot * (1.0f / 4096.0f) + 1.1920928955078125e-07f);
    ushort4* ob = (ushort4*)(Xb + row * 4096);
    #pragma unroll
    for (int i = 0; i < 4; ++i) {
        ushort4 o;
        o.x = f2bf(v[i].x * scale);
        o.y = f2bf(v[i].y * scale);
        o.z = f2bf(v[i].z * scale);
        o.w = f2bf(v[i].w * scale);
        ob[i * 256 + t] = o;
    }
}

// ---------- kernel 3: grouped GEMM, bf16 MFMA, m97-style 128x128 tile ----------
// Xb: [8192][4096] bf16 (normalized x), Wq: [4096][1024] bf16 (B^T layout),
// Out: [8192][4096] fp32.  out[m][n] = sum_k Xb[m][(n>>10)*1024 + k] * Wq[n][k]
#define BK 64
__global__ __launch_bounds__(256, 2) void gemm_kernel(const unsigned short* __restrict__ Xb,
                                                      const unsigned short* __restrict__ Wq,
                                                      float* __restrict__ Out) {
    __shared__ unsigned short lsA[128 * BK];
    __shared__ unsigned short lsB[128 * BK];

    const int t = threadIdx.x;
    const int lane = t & 63;
    const int wv = t >> 6;
    const int wr = wv >> 1, wc = wv & 1;

    const int bm0 = (blockIdx.x & 63) * 128;   // M block (M=8192 -> 64 blocks)
    const int bn0 = (blockIdx.x >> 6) * 128;   // N block (N=4096 -> 32 blocks)
    const int g = bn0 >> 10;                   // group id
    const long long abase = (long long)bm0 * 4096 + g * 1024;

    f32x4 acc[4][4];
    #pragma unroll
    for (int i = 0; i < 4; ++i)
        #pragma unroll
        for (int j = 0; j < 4; ++j) acc[i][j] = (f32x4){0.f, 0.f, 0.f, 0.f};

    const int srow = t >> 3;          // staging row within 32-row chunk
    const int scol = (t & 7) * 8;     // staging col (elements)

    for (int kt = 0; kt < 1024 / BK; ++kt) {
        const int k0 = kt * BK;
        #pragma unroll
        for (int c = 0; c < 4; ++c) {
            const unsigned short* gp = Xb + abase + (long long)(c * 32 + srow) * 4096 + k0 + scol;
            async16(gp, (char*)lsA + c * 4096 + t * 16);
        }
        #pragma unroll
        for (int c = 0; c < 4; ++c) {
            const unsigned short* gp = Wq + (long long)(bn0 + c * 32 + srow) * 1024 + k0 + scol;
            async16(gp, (char*)lsB + c * 4096 + t * 16);
        }
        __syncthreads();   // drains vmcnt (compiler emits full waitcnt before s_barrier)

        #pragma unroll
        for (int ks = 0; ks < 2; ++ks) {
            bf16x8 afr[4], bfr[4];
            const int kk = ks * 32 + (lane >> 4) * 8;
            #pragma unroll
            for (int mi = 0; mi < 4; ++mi) {
                const int row = wr * 64 + mi * 16 + (lane & 15);
                afr[mi] = *(const bf16x8*)&lsA[row * BK + kk];
            }
            #pragma unroll
            for (int ni = 0; ni < 4; ++ni) {
                const int row = wc * 64 + ni * 16 + (lane & 15);
                bfr[ni] = *(const bf16x8*)&lsB[row * BK + kk];
            }
            #pragma unroll
            for (int mi = 0; mi < 4; ++mi)
                #pragma unroll
                for (int ni = 0; ni < 4; ++ni)
                    acc[mi][ni] = __builtin_amdgcn_mfma_f32_16x16x32_bf16(afr[mi], bfr[ni], acc[mi][ni], 0, 0, 0);
        }
        __syncthreads();
    }

    // epilogue: C/D layout col=lane&15, row=(lane>>4)*4+reg  [m89-verified]
    #pragma unroll
    for (int mi = 0; mi < 4; ++mi) {
        #pragma unroll
        for (int ni = 0; ni < 4; ++ni) {
            const int col = bn0 + wc * 64 + ni * 16 + (lane & 15);
            const int rowb = bm0 + wr * 64 + mi * 16 + (lane >> 4) * 4;
            #pragma unroll
            for (int r = 0; r < 4; ++r)
                Out[(long long)(rowb + r) * 4096 + col] = acc[mi][ni][r];
        }
    }
}

// ---------- launcher ----------
extern "C" void kernel_launch(void* const* d_in, const int* in_sizes, int n_in,
                              void* d_out, int out_size, void* d_ws, size_t ws_size,
                              hipStream_t stream) {
    const float* x = (const float*)d_in[0];     // (2,4096,4096) fp32
    const float* w = (const float*)d_in[1];     // (4096,1024) fp32
    float* out = (float*)d_out;                 // (2,4096,4096) fp32

    unsigned short* xb = (unsigned short*)d_ws;                   // 8192*4096 bf16 = 64 MiB
    unsigned short* wq = xb + (size_t)8192 * 4096;                // 4096*1024 bf16 = 8 MiB

    quant_kernel<<<4096 * 1024 / 256, 256, 0, stream>>>(w, wq);
    norm_kernel<<<8192, 256, 0, stream>>>(x, xb);
    gemm_kernel<<<2048, 256, 0, stream>>>(xb, wq, out);
}

// Round 2
// 336.100 us; speedup vs baseline: 1.0025x; 1.0025x over previous
//
#include <hip/hip_runtime.h>
#include <hip/hip_bf16.h>
#include <stdint.h>

// ---------- helpers ----------
__device__ __forceinline__ unsigned short f2bf(float f) {
    __hip_bfloat16 h = __float2bfloat16(f);   // RNE, matches JAX astype
    return *reinterpret_cast<unsigned short*>(&h);
}
__device__ __forceinline__ float bf2f(unsigned short u) {
    __hip_bfloat16 h = *reinterpret_cast<__hip_bfloat16*>(&u);
    return __bfloat162float(h);
}

typedef __attribute__((ext_vector_type(8))) short bf16x8;
typedef __attribute__((ext_vector_type(4))) float f32x4;

__device__ __forceinline__ void async16(const void* g, void* l) {
    __builtin_amdgcn_global_load_lds(
        (const __attribute__((address_space(1))) unsigned int*)g,
        (__attribute__((address_space(3))) unsigned int*)l,
        16, 0, 0);
}

// ---------- kernel 1: ternary-quantize weight (replicates JAX bf16 per-op rounding) ----------
__global__ __launch_bounds__(256) void quant_kernel(const float* __restrict__ W,
                                                    unsigned short* __restrict__ Wq) {
    int idx = blockIdx.x * 256 + threadIdx.x;
    float wf = W[idx];
    float wbf = bf2f(f2bf(wf));            // w = weight.astype(bf16)
    float a = fabsf(wbf);
    float s = a;
    #pragma unroll
    for (int off = 32; off; off >>= 1) s += __shfl_xor(s, off, 64);
    float mean = s * (1.0f / 64.0f);       // f32 accumulation (JAX upcasts bf16 mean)
    float sf = bf2f(f2bf(mean));           // cast result back to bf16
    sf = fmaxf(sf, 1.0011718e-08f);        // clip(scale, 1e-8) in bf16 domain
    float quot = bf2f(f2bf(wbf / sf));     // bf16 division = f32 div then bf16 round
    float q = rintf(quot);                 // round half-to-even
    q = fminf(1.0f, fmaxf(-1.0f, q));
    float qs = q * sf;                     // exact bf16 value (q in {-1,0,1})
    float d  = bf2f(f2bf(qs - wbf));       // bf16 subtraction rounding
    Wq[idx] = f2bf(wbf + d);               // bf16 add rounding -> forward weight
}

// ---------- kernel 2: RMS-norm rows of 4096, write bf16 ----------
__global__ __launch_bounds__(256) void norm_kernel(const float* __restrict__ X,
                                                   unsigned short* __restrict__ Xb) {
    __shared__ float red[4];
    const long long row = blockIdx.x;
    const float4* xr = (const float4*)(X + row * 4096);
    const int t = threadIdx.x;
    float4 v[4];
    float ss = 0.f;
    #pragma unroll
    for (int i = 0; i < 4; ++i) {
        v[i] = xr[i * 256 + t];
        ss += v[i].x * v[i].x + v[i].y * v[i].y + v[i].z * v[i].z + v[i].w * v[i].w;
    }
    #pragma unroll
    for (int off = 32; off; off >>= 1) ss += __shfl_xor(ss, off, 64);
    if ((t & 63) == 0) red[t >> 6] = ss;
    __syncthreads();
    const float tot = red[0] + red[1] + red[2] + red[3];
    const float scale = 1.0f / sqrtf(tot * (1.0f / 4096.0f) + 1.1920928955078125e-07f);
    ushort4* ob = (ushort4*)(Xb + row * 4096);
    #pragma unroll
    for (int i = 0; i < 4; ++i) {
        ushort4 o;
        o.x = f2bf(v[i].x * scale);
        o.y = f2bf(v[i].y * scale);
        o.z = f2bf(v[i].z * scale);
        o.w = f2bf(v[i].w * scale);
        ob[i * 256 + t] = o;
    }
}

// ---------- kernel 3: grouped GEMM, 256x256 tile, BK=32, quad-buffered deep pipeline ----------
// Xb: [8192][4096] bf16 (normalized x), Wq: [4096][1024] bf16 (B^T layout),
// Out: [8192][4096] fp32.  out[m][n] = sum_k Xb[m][(n>>10)*1024 + k] * Wq[n][k]
// 8 waves: WARPS_M=2 x WARPS_N=4, per-wave output 128x64 (acc[8][4] f32x4).
// LDS: 4 buffers x (A 256x32 + B 256x32) bf16 = 128 KiB.
// Swizzle (T2, rule #21): linear gload_lds dest + pre-swizzled global source
//   colblk ^= (row>>1)&3  + same XOR on ds_read addr.
__global__ __launch_bounds__(512, 2) void gemm_kernel(const unsigned short* __restrict__ Xb,
                                                      const unsigned short* __restrict__ Wq,
                                                      float* __restrict__ Out) {
    __shared__ unsigned short lsA[4][256 * 32];
    __shared__ unsigned short lsB[4][256 * 32];

    const int tid = threadIdx.x;
    const int lane = tid & 63;
    const int wv = tid >> 6;          // 0..7
    const int wr = wv >> 2;           // 0..1
    const int wc = wv & 3;            // 0..3

    // T1: XCD-bijective swizzle (512 blocks % 8 == 0)
    const int bid = blockIdx.x;
    const int swz = (bid & 7) * 64 + (bid >> 3);
    const int bm0 = (swz & 31) * 256;     // M block
    const int bn0 = (swz >> 5) * 256;     // N block (group-major inside 4096)
    const int g = bn0 >> 10;              // group id

    // staging: thread t covers row=(t>>2)+128*round, 16B colblock c=(t&3), swizzled source
    const int srow = tid >> 2;                          // 0..127
    const int cswz = (tid & 3) ^ ((tid >> 3) & 3);      // (row>>1)&3 == (tid>>3)&3
    const unsigned short* pA0 = Xb + (long long)(bm0 + srow) * 4096 + g * 1024 + cswz * 8;
    const unsigned short* pA1 = pA0 + (long long)128 * 4096;
    const unsigned short* pB0 = Wq + (long long)(bn0 + srow) * 1024 + cswz * 8;
    const unsigned short* pB1 = pB0 + (long long)128 * 1024;
    const int ldst = tid * 8;   // linear LDS dest (elements); +4096 for round 1

    // frag-read offsets (elements), same XOR on read side
    const int cb = (lane >> 4) ^ ((lane >> 1) & 3);
    const int aOff = (wr * 128 + (lane & 15)) * 32 + cb * 8;
    const int bOff = (wc * 64 + (lane & 15)) * 32 + cb * 8;

    f32x4 acc[8][4];
    #pragma unroll
    for (int i = 0; i < 8; ++i)
        #pragma unroll
        for (int j = 0; j < 4; ++j) acc[i][j] = (f32x4){0.f, 0.f, 0.f, 0.f};

    const int T = 32;   // K-tiles: 1024 / BK(32)

    // prologue: stage tiles 0..2 (12 loads/wave), wait so tile 0 resident, 8 in flight
    #pragma unroll
    for (int pt = 0; pt < 3; ++pt) {
        async16(pA0 + pt * 32, &lsA[pt][ldst]);
        async16(pA1 + pt * 32, &lsA[pt][ldst + 4096]);
        async16(pB0 + pt * 32, &lsB[pt][ldst]);
        async16(pB1 + pt * 32, &lsB[pt][ldst + 4096]);
    }
    asm volatile("s_waitcnt vmcnt(8)" ::: "memory");
    __builtin_amdgcn_s_barrier();

    for (int t = 0; t < T; ++t) {
        const unsigned short* sA = lsA[t & 3];
        const unsigned short* sB = lsB[t & 3];
        bf16x8 afr[4], bfr[4];

        // ---- phase 0: read B(all) + A(lower half); issue A-stage of tile t+3 ----
        #pragma unroll
        for (int ni = 0; ni < 4; ++ni) bfr[ni] = *(const bf16x8*)&sB[bOff + ni * 512];
        #pragma unroll
        for (int i = 0; i < 4; ++i) afr[i] = *(const bf16x8*)&sA[aOff + i * 512];
        if (t + 3 < T) {
            unsigned short* dA = lsA[(t + 3) & 3];
            async16(pA0 + (t + 3) * 32, dA + ldst);
            async16(pA1 + (t + 3) * 32, dA + ldst + 4096);
        }
        __builtin_amdgcn_s_barrier();
        __builtin_amdgcn_s_setprio(1);
        #pragma unroll
        for (int i = 0; i < 4; ++i)
            #pragma unroll
            for (int ni = 0; ni < 4; ++ni)
                acc[i][ni] = __builtin_amdgcn_mfma_f32_16x16x32_bf16(afr[i], bfr[ni], acc[i][ni], 0, 0, 0);
        __builtin_amdgcn_s_setprio(0);
        __builtin_amdgcn_s_barrier();

        // ---- phase 1: read A(upper half); issue B-stage of tile t+3 ----
        #pragma unroll
        for (int i = 0; i < 4; ++i) afr[i] = *(const bf16x8*)&sA[aOff + (i + 4) * 512];
        if (t + 3 < T) {
            unsigned short* dB = lsB[(t + 3) & 3];
            async16(pB0 + (t + 3) * 32, dB + ldst);
            async16(pB1 + (t + 3) * 32, dB + ldst + 4096);
        }
        __builtin_amdgcn_s_barrier();
        __builtin_amdgcn_s_setprio(1);
        #pragma unroll
        for (int i = 0; i < 4; ++i)
            #pragma unroll
            for (int ni = 0; ni < 4; ++ni)
                acc[i + 4][ni] = __builtin_amdgcn_mfma_f32_16x16x32_bf16(afr[i], bfr[ni], acc[i + 4][ni], 0, 0, 0);
        __builtin_amdgcn_s_setprio(0);

        // counted vmcnt once per K-tile (per-wave, BEFORE the closing barrier):
        // steady state: tiles t+2,t+3 in flight (8 loads) after retiring t+1's 4.
        if (t < T - 3)       asm volatile("s_waitcnt vmcnt(8)" ::: "memory");
        else if (t == T - 3) asm volatile("s_waitcnt vmcnt(4)" ::: "memory");
        else if (t == T - 2) asm volatile("s_waitcnt vmcnt(0)" ::: "memory");
        __builtin_amdgcn_s_barrier();
    }

    // epilogue: C/D layout col=lane&15, row=(lane>>4)*4+reg  [m89-verified]
    #pragma unroll
    for (int mi = 0; mi < 8; ++mi) {
        #pragma unroll
        for (int ni = 0; ni < 4; ++ni) {
            const int col = bn0 + wc * 64 + ni * 16 + (lane & 15);
            const int rowb = bm0 + wr * 128 + mi * 16 + (lane >> 4) * 4;
            #pragma unroll
            for (int r = 0; r < 4; ++r)
                Out[(long long)(rowb + r) * 4096 + col] = acc[mi][ni][r];
        }
    }
}

// ---------- launcher ----------
extern "C" void kernel_launch(void* const* d_in, const int* in_sizes, int n_in,
                              void* d_out, int out_size, void* d_ws, size_t ws_size,
                              hipStream_t stream) {
    const float* x = (const float*)d_in[0];     // (2,4096,4096) fp32
    const float* w = (const float*)d_in[1];     // (4096,1024) fp32
    float* out = (float*)d_out;                 // (2,4096,4096) fp32

    unsigned short* xb = (unsigned short*)d_ws;                   // 8192*4096 bf16 = 64 MiB
    unsigned short* wq = xb + (size_t)8192 * 4096;                // 4096*1024 bf16 = 8 MiB

    quant_kernel<<<4096 * 1024 / 256, 256, 0, stream>>>(w, wq);
    norm_kernel<<<8192, 256, 0, stream>>>(x, xb);
    gemm_kernel<<<512, 512, 0, stream>>>(xb, wq, out);
}

// Round 3
// 321.956 us; speedup vs baseline: 1.0465x; 1.0439x over previous
//
#include <hip/hip_runtime.h>
#include <hip/hip_bf16.h>
#include <stdint.h>

// ---------- helpers ----------
__device__ __forceinline__ unsigned short f2bf(float f) {
    __hip_bfloat16 h = __float2bfloat16(f);   // RNE, matches JAX astype
    return *reinterpret_cast<unsigned short*>(&h);
}
__device__ __forceinline__ float bf2f(unsigned short u) {
    __hip_bfloat16 h = *reinterpret_cast<__hip_bfloat16*>(&u);
    return __bfloat162float(h);
}

typedef __attribute__((ext_vector_type(8))) short bf16x8;
typedef __attribute__((ext_vector_type(4))) float f32x4;

__device__ __forceinline__ void async16(const void* g, void* l) {
    __builtin_amdgcn_global_load_lds(
        (const __attribute__((address_space(1))) unsigned int*)g,
        (__attribute__((address_space(3))) unsigned int*)l,
        16, 0, 0);
}

// ---------- kernel 1: ternary-quantize weight (replicates JAX bf16 per-op rounding) ----------
__global__ __launch_bounds__(256) void quant_kernel(const float* __restrict__ W,
                                                    unsigned short* __restrict__ Wq) {
    int idx = blockIdx.x * 256 + threadIdx.x;
    float wf = W[idx];
    float wbf = bf2f(f2bf(wf));            // w = weight.astype(bf16)
    float a = fabsf(wbf);
    float s = a;
    #pragma unroll
    for (int off = 32; off; off >>= 1) s += __shfl_xor(s, off, 64);
    float mean = s * (1.0f / 64.0f);       // f32 accumulation (JAX upcasts bf16 mean)
    float sf = bf2f(f2bf(mean));           // cast result back to bf16
    sf = fmaxf(sf, 1.0011718e-08f);        // clip(scale, 1e-8) in bf16 domain
    float quot = bf2f(f2bf(wbf / sf));     // bf16 division = f32 div then bf16 round
    float q = rintf(quot);                 // round half-to-even
    q = fminf(1.0f, fmaxf(-1.0f, q));
    float qs = q * sf;                     // exact bf16 value (q in {-1,0,1})
    float d  = bf2f(f2bf(qs - wbf));       // bf16 subtraction rounding
    Wq[idx] = f2bf(wbf + d);               // bf16 add rounding -> forward weight
}

// ---------- kernel 2: RMS-norm rows of 4096, write bf16 ----------
__global__ __launch_bounds__(256) void norm_kernel(const float* __restrict__ X,
                                                   unsigned short* __restrict__ Xb) {
    __shared__ float red[4];
    const long long row = blockIdx.x;
    const float4* xr = (const float4*)(X + row * 4096);
    const int t = threadIdx.x;
    float4 v[4];
    float ss = 0.f;
    #pragma unroll
    for (int i = 0; i < 4; ++i) {
        v[i] = xr[i * 256 + t];
        ss += v[i].x * v[i].x + v[i].y * v[i].y + v[i].z * v[i].z + v[i].w * v[i].w;
    }
    #pragma unroll
    for (int off = 32; off; off >>= 1) ss += __shfl_xor(ss, off, 64);
    if ((t & 63) == 0) red[t >> 6] = ss;
    __syncthreads();
    const float tot = red[0] + red[1] + red[2] + red[3];
    const float scale = 1.0f / sqrtf(tot * (1.0f / 4096.0f) + 1.1920928955078125e-07f);
    ushort4* ob = (ushort4*)(Xb + row * 4096);
    #pragma unroll
    for (int i = 0; i < 4; ++i) {
        ushort4 o;
        o.x = f2bf(v[i].x * scale);
        o.y = f2bf(v[i].y * scale);
        o.z = f2bf(v[i].z * scale);
        o.w = f2bf(v[i].w * scale);
        ob[i * 256 + t] = o;
    }
}

// ---------- kernel 3: grouped GEMM, 256x256 tile, BK=64, m201 8-phase schedule ----------
// Xb: [8192][4096] bf16, Wq: [4096][1024] bf16 (B^T), Out: [8192][4096] fp32.
// out[m][n] = sum_k Xb[m][(n>>10)*1024 + k] * Wq[n][k]
// 8 waves (2M x 4N), per-wave 128x64 output. 16 K-tiles of 64; 8 iterations,
// 8 phases/iter (4 per K-tile, one C-quadrant of 16 MFMA each).
// LDS 128 KiB: 2 dbuf x (A[256][64] + B[256][64]) bf16, halves staged separately.
// Swizzle: kb ^= row&7 on pre-swizzled global source AND ds_read addr (rule #21).
// Stage->phase assignment proven WAR-safe: each stage issues after the chip-wide
// closing barrier of the last phase reading that region. vmcnt(4) at P4/P8 only.
__global__ __launch_bounds__(512, 2) void gemm_kernel(const unsigned short* __restrict__ Xb,
                                                      const unsigned short* __restrict__ Wq,
                                                      float* __restrict__ Out) {
    __shared__ __attribute__((aligned(16))) unsigned short ls[65536];   // 128 KiB

    const int tid = threadIdx.x;
    const int lane = tid & 63;
    const int laneR = lane & 15;
    const int wv = tid >> 6;
    const int wr = wv >> 2;           // 0..1
    const int wc = wv & 3;            // 0..3

    // T1: XCD-bijective swizzle (512 % 8 == 0)
    const int bid = blockIdx.x;
    const int swz = (bid & 7) * 64 + (bid >> 3);
    const int bm0 = (swz & 31) * 256;
    const int bn0 = (swz >> 5) * 256;
    const int g = bn0 >> 10;

    // staging: thread covers row srow (+64/+128/+192 via half/j), colblock (tid&7) pre-swizzled
    const int srow = tid >> 3;                              // 0..63
    const int cswz8 = (((tid & 7) ^ (srow & 7)) << 3);      // element offset in row
    const unsigned short* aG = Xb + (long long)(bm0 + srow) * 4096 + g * 1024 + cswz8;
    const unsigned short* bG = Wq + (long long)(bn0 + srow) * 1024 + cswz8;

    // read-side swizzle: kb = ks*4 + (lane>>4), slot = kb ^ (row&7), row&7 == lane&7
    const int col0 = (((lane >> 4) ^ (lane & 7)) << 3);
    const int col1 = col0 ^ 32;

    // LDS region bases (elements): buf0 A, buf0 B, buf1 A, buf1 B
    enum { A0 = 0, B0 = 16384, A1 = 32768, B1 = 49152 };

    const int aRow = (wr * 128 + laneR) * 64;   // + mh*4096 + mi*1024
    const int bRow = (wc * 64 + laneR) * 64;    // + ni*1024

#define STAGE_A(base, kt, h) do { \
    async16(aG + ((long long)((h) * 128) * 4096 + (kt) * 64),      ls + (base) + (h) * 8192 + tid * 8); \
    async16(aG + ((long long)((h) * 128 + 64) * 4096 + (kt) * 64), ls + (base) + (h) * 8192 + 4096 + tid * 8); \
} while (0)
#define STAGE_B(base, kt, h) do { \
    async16(bG + ((long long)((h) * 128) * 1024 + (kt) * 64),      ls + (base) + (h) * 8192 + tid * 8); \
    async16(bG + ((long long)((h) * 128 + 64) * 1024 + (kt) * 64), ls + (base) + (h) * 8192 + 4096 + tid * 8); \
} while (0)
#define LD(off) (*(const bf16x8*)(ls + (off)))
#define MFMA_Q(MB, NB, bb) do { \
    _Pragma("unroll") \
    for (int mi = 0; mi < 4; ++mi) { \
        _Pragma("unroll") \
        for (int ni = 0; ni < 2; ++ni) { \
            acc[(MB) + mi][(NB) + ni] = __builtin_amdgcn_mfma_f32_16x16x32_bf16(a[mi][0], bb[ni][0], acc[(MB) + mi][(NB) + ni], 0, 0, 0); \
            acc[(MB) + mi][(NB) + ni] = __builtin_amdgcn_mfma_f32_16x16x32_bf16(a[mi][1], bb[ni][1], acc[(MB) + mi][(NB) + ni], 0, 0, 0); \
        } \
    } \
} while (0)
#define BAR() __builtin_amdgcn_s_barrier()
#define PRIO1() __builtin_amdgcn_s_setprio(1)
#define PRIO0() __builtin_amdgcn_s_setprio(0)

    f32x4 acc[8][4];
    #pragma unroll
    for (int i = 0; i < 8; ++i)
        #pragma unroll
        for (int j = 0; j < 4; ++j) acc[i][j] = (f32x4){0.f, 0.f, 0.f, 0.f};

    bf16x8 a[4][2], b[2][2], c[2][2];

    // ---- prologue: kt0 full into buf0 (8 loads), B(kt1) into buf1 (4 loads)
    STAGE_A(A0, 0, 0); STAGE_A(A0, 0, 1);
    STAGE_B(B0, 0, 0); STAGE_B(B0, 0, 1);
    STAGE_B(B1, 1, 0); STAGE_B(B1, 1, 1);
    asm volatile("s_waitcnt vmcnt(4)" ::: "memory");   // kt0 resident; B(kt1) in flight
    BAR();

    #pragma unroll 1
    for (int it = 0; it < 8; ++it) {
        const int kt0 = it * 2, kt1 = kt0 + 1;
        const bool pf = (it < 7);

        // ---- P1: buf0 quad(0,0); stage A_h0(kt1)->buf1 ----
        #pragma unroll
        for (int ni = 0; ni < 2; ++ni) { b[ni][0] = LD(B0 + bRow + ni * 1024 + col0); b[ni][1] = LD(B0 + bRow + ni * 1024 + col1); }
        #pragma unroll
        for (int mi = 0; mi < 4; ++mi) { a[mi][0] = LD(A0 + aRow + mi * 1024 + col0); a[mi][1] = LD(A0 + aRow + mi * 1024 + col1); }
        STAGE_A(A1, kt1, 0);
        BAR(); PRIO1(); MFMA_Q(0, 0, b); PRIO0(); BAR();

        // ---- P2: buf0 quad(0,1); stage A_h1(kt1)->buf1 ----
        #pragma unroll
        for (int ni = 0; ni < 2; ++ni) { c[ni][0] = LD(B0 + bRow + (ni + 2) * 1024 + col0); c[ni][1] = LD(B0 + bRow + (ni + 2) * 1024 + col1); }
        STAGE_A(A1, kt1, 1);
        BAR(); PRIO1(); MFMA_Q(0, 2, c); PRIO0(); BAR();

        // ---- P3: buf0 quad(1,0); stage B_h0(kt0+2)->buf0 (B reads done at P2 close) ----
        #pragma unroll
        for (int mi = 0; mi < 4; ++mi) { a[mi][0] = LD(A0 + aRow + 4096 + mi * 1024 + col0); a[mi][1] = LD(A0 + aRow + 4096 + mi * 1024 + col1); }
        if (pf) STAGE_B(B0, kt0 + 2, 0);
        BAR(); PRIO1(); MFMA_Q(4, 0, b); PRIO0(); BAR();

        // ---- P4: buf0 quad(1,1); stage B_h1(kt0+2); counted vmcnt ----
        if (pf) STAGE_B(B0, kt0 + 2, 1);
        BAR(); PRIO1(); MFMA_Q(4, 2, c); PRIO0();
        if (pf) { asm volatile("s_waitcnt vmcnt(4)" ::: "memory"); }
        else    { asm volatile("s_waitcnt vmcnt(0)" ::: "memory"); }
        BAR();

        // ---- P5: buf1 quad(0,0); stage A_h0(kt0+2)->buf0 (A reads done at P3 close) ----
        #pragma unroll
        for (int ni = 0; ni < 2; ++ni) { b[ni][0] = LD(B1 + bRow + ni * 1024 + col0); b[ni][1] = LD(B1 + bRow + ni * 1024 + col1); }
        #pragma unroll
        for (int mi = 0; mi < 4; ++mi) { a[mi][0] = LD(A1 + aRow + mi * 1024 + col0); a[mi][1] = LD(A1 + aRow + mi * 1024 + col1); }
        if (pf) STAGE_A(A0, kt0 + 2, 0);
        BAR(); PRIO1(); MFMA_Q(0, 0, b); PRIO0(); BAR();

        // ---- P6: buf1 quad(0,1); stage A_h1(kt0+2)->buf0 ----
        #pragma unroll
        for (int ni = 0; ni < 2; ++ni) { c[ni][0] = LD(B1 + bRow + (ni + 2) * 1024 + col0); c[ni][1] = LD(B1 + bRow + (ni + 2) * 1024 + col1); }
        if (pf) STAGE_A(A0, kt0 + 2, 1);
        BAR(); PRIO1(); MFMA_Q(0, 2, c); PRIO0(); BAR();

        // ---- P7: buf1 quad(1,0); stage B_h0(kt1+2)->buf1 (buf1 B reads done at P6 close) ----
        #pragma unroll
        for (int mi = 0; mi < 4; ++mi) { a[mi][0] = LD(A1 + aRow + 4096 + mi * 1024 + col0); a[mi][1] = LD(A1 + aRow + 4096 + mi * 1024 + col1); }
        if (pf) STAGE_B(B1, kt1 + 2, 0);
        BAR(); PRIO1(); MFMA_Q(4, 0, b); PRIO0(); BAR();

        // ---- P8: buf1 quad(1,1); stage B_h1(kt1+2); counted vmcnt ----
        if (pf) STAGE_B(B1, kt1 + 2, 1);
        BAR(); PRIO1(); MFMA_Q(4, 2, c); PRIO0();
        if (pf) { asm volatile("s_waitcnt vmcnt(4)" ::: "memory"); }
        BAR();
    }

    // epilogue: C/D layout col=lane&15, row=(lane>>4)*4+reg  [m89-verified]
    #pragma unroll
    for (int mi = 0; mi < 8; ++mi) {
        #pragma unroll
        for (int ni = 0; ni < 4; ++ni) {
            const int colo = bn0 + wc * 64 + ni * 16 + laneR;
            const int rowb = bm0 + wr * 128 + mi * 16 + (lane >> 4) * 4;
            #pragma unroll
            for (int r = 0; r < 4; ++r)
                Out[(long long)(rowb + r) * 4096 + colo] = acc[mi][ni][r];
        }
    }
#undef STAGE_A
#undef STAGE_B
#undef LD
#undef MFMA_Q
#undef BAR
#undef PRIO1
#undef PRIO0
}

// ---------- launcher ----------
extern "C" void kernel_launch(void* const* d_in, const int* in_sizes, int n_in,
                              void* d_out, int out_size, void* d_ws, size_t ws_size,
                              hipStream_t stream) {
    const float* x = (const float*)d_in[0];     // (2,4096,4096) fp32
    const float* w = (const float*)d_in[1];     // (4096,1024) fp32
    float* out = (float*)d_out;                 // (2,4096,4096) fp32

    unsigned short* xb = (unsigned short*)d_ws;                   // 8192*4096 bf16 = 64 MiB
    unsigned short* wq = xb + (size_t)8192 * 4096;                // 4096*1024 bf16 = 8 MiB

    quant_kernel<<<4096 * 1024 / 256, 256, 0, stream>>>(w, wq);
    norm_kernel<<<8192, 256, 0, stream>>>(x, xb);
    gemm_kernel<<<512, 512, 0, stream>>>(xb, wq, out);
}